// Round 8
// baseline (1717.119 us; speedup 1.0000x reference)
//
#include <hip/hip_runtime.h>
#include <stdint.h>

#define N_NODES   50000
#define N_GENES   512
#define N_EDGES   800000
#define N_ITERS   5
#define TOTAL_ELEMS 25600000u

#define C_CHUNKS  250
#define CHUNK_E   3200          // 250 * 3200 = 800000; 3200/64 = 50 subchunks exactly

// ws layout sizes (bytes)
#define X_WS_BYTES   102400000ull
#define IMP_BYTES    3200000ull            // 64 B per row: byte per lane, 8 gene-flags/bit
#define CNT_BYTES    200000ull
#define PTR_BYTES    200004ull
#define CCOL_BYTES   3200000ull
#define CW_BYTES     3200000ull
#define WS_NEEDED (X_WS_BYTES + IMP_BYTES + CNT_BYTES + PTR_BYTES + CCOL_BYTES + CW_BYTES)
// hist (250*50000*4 = 50 MB) aliases the x_ws region: dead before x_ws first written.

// ---------- JAX threefry2x32 (20 rounds), exact replica ----------
__host__ __device__ __forceinline__ uint32_t rotl32(uint32_t x, int r) {
  return (x << r) | (x >> (32 - r));
}

__host__ __device__ __forceinline__ void threefry2x32(uint32_t k0, uint32_t k1,
                                                      uint32_t x0, uint32_t x1,
                                                      uint32_t& o0, uint32_t& o1) {
  uint32_t k2 = k0 ^ k1 ^ 0x1BD11BDAu;
  x0 += k0; x1 += k1;
  x0 += x1; x1 = rotl32(x1, 13) ^ x0;
  x0 += x1; x1 = rotl32(x1, 15) ^ x0;
  x0 += x1; x1 = rotl32(x1, 26) ^ x0;
  x0 += x1; x1 = rotl32(x1, 6)  ^ x0;
  x0 += k1; x1 += k2 + 1u;
  x0 += x1; x1 = rotl32(x1, 17) ^ x0;
  x0 += x1; x1 = rotl32(x1, 29) ^ x0;
  x0 += x1; x1 = rotl32(x1, 16) ^ x0;
  x0 += x1; x1 = rotl32(x1, 24) ^ x0;
  x0 += k2; x1 += k0 + 2u;
  x0 += x1; x1 = rotl32(x1, 13) ^ x0;
  x0 += x1; x1 = rotl32(x1, 15) ^ x0;
  x0 += x1; x1 = rotl32(x1, 26) ^ x0;
  x0 += x1; x1 = rotl32(x1, 6)  ^ x0;
  x0 += k0; x1 += k1 + 3u;
  x0 += x1; x1 = rotl32(x1, 17) ^ x0;
  x0 += x1; x1 = rotl32(x1, 29) ^ x0;
  x0 += x1; x1 = rotl32(x1, 16) ^ x0;
  x0 += x1; x1 = rotl32(x1, 24) ^ x0;
  x0 += k1; x1 += k2 + 4u;
  x0 += x1; x1 = rotl32(x1, 13) ^ x0;
  x0 += x1; x1 = rotl32(x1, 15) ^ x0;
  x0 += x1; x1 = rotl32(x1, 26) ^ x0;
  x0 += x1; x1 = rotl32(x1, 6)  ^ x0;
  x0 += k2; x1 += k0 + 5u;
  o0 = x0; o1 = x1;
}

// threefry_partitionable=True (modern JAX default) 32-bit random bits:
// counter-mode over the 64-bit flat index j -> (0, j); xor-fold: o0 ^ o1.
__device__ __forceinline__ uint32_t jax_bits_part32(uint32_t k0, uint32_t k1, uint32_t j) {
  uint32_t o0, o1;
  threefry2x32(k0, k1, 0u, j, o0, o1);
  return o0 ^ o1;
}

// ---------- order-preserving CSR build ----------
__global__ void chunk_hist(const int* __restrict__ rows, int* __restrict__ hist) {
  int c = blockIdx.x;
  int base = c * CHUNK_E;
  int* h = hist + (size_t)c * N_NODES;
  for (int i = threadIdx.x; i < CHUNK_E; i += blockDim.x)
    atomicAdd(&h[rows[base + i]], 1);
}

// per-row exclusive scan across chunks; emits per-row totals
__global__ void row_scan(int* __restrict__ hist, int* __restrict__ cnt) {
  int r = blockIdx.x * blockDim.x + threadIdx.x;
  if (r >= N_NODES) return;
  int run = 0;
  for (int c = 0; c < C_CHUNKS; ++c) {
    size_t idx = (size_t)c * N_NODES + r;
    int t = hist[idx];
    hist[idx] = run;
    run += t;
  }
  cnt[r] = run;
}

__global__ void scan_counts(int* __restrict__ cnt, int* __restrict__ ptr) {
  const int T = 256;
  const int CH = (N_NODES + T - 1) / T;  // 196
  __shared__ int sums[T];
  int t = threadIdx.x;
  int lo = t * CH;
  int hi = min(lo + CH, N_NODES);
  int s = 0;
  for (int i = lo; i < hi; ++i) s += cnt[i];
  sums[t] = s;
  __syncthreads();
  for (int off = 1; off < T; off <<= 1) {
    int u = (t >= off) ? sums[t - off] : 0;
    __syncthreads();
    sums[t] += u;
    __syncthreads();
  }
  int run = sums[t] - s;
  for (int i = lo; i < hi; ++i) { int c = cnt[i]; ptr[i] = run; run += c; }
  if (t == T - 1) ptr[N_NODES] = run;
}

// parallel order-preserving scatter: one wave per chunk (see R6 notes).
__global__ __launch_bounds__(64) void scatter_par(
    const int* __restrict__ rows, const int* __restrict__ cols,
    const float* __restrict__ w, const int* __restrict__ ptr,
    int* __restrict__ hist, int* __restrict__ ccol, float* __restrict__ cw) {
  int c = blockIdx.x;
  int lane = threadIdx.x;
  int* h = hist + (size_t)c * N_NODES;
  int base = c * CHUNK_E;
  for (int sub = 0; sub < CHUNK_E / 64; ++sub) {
    int e = base + sub * 64 + lane;
    int r = rows[e];
    int rank = 0, count = 0, lastlane = 0;
    #pragma unroll 8
    for (int i = 0; i < 64; ++i) {
      int ri = __shfl(r, i, 64);
      if (ri == r) {
        count++;
        if (i < lane) rank++;
        lastlane = i;          // i ascending -> ends at max matching lane
      }
    }
    int old = 0;
    if (lane == lastlane) old = atomicAdd(&h[r], count);
    old = __shfl(old, lastlane, 64);   // data dep -> vmcnt drain before next sub
    int pos = ptr[r] + old + rank;
    ccol[pos] = cols[e];
    cw[pos]   = w[e];
  }
}

// transposed LDS index for bucket b: stride-64 across a lane's 4 buckets
__device__ __forceinline__ int tr(uint32_t b) {
  return (int)(((b & 3u) << 6) | (b >> 2));
}

// ---------- fused propagate + select: one wave per row ----------
// orig-free: existing <=> xprev[j]!=0 && !impbit[j] (orig!=0 positions keep
// orig's value in xprev forever; orig==0 positions are nonzero only while
// their imp bit is set). Keeps output bit-identical while shrinking the L3
// working set to xprev+xnext+CSR+imp ~ 214 MB < 256 MB Infinity Cache.
// XLA-CPU scatter semantics: ascending edge order, mul/add rounded separately.
__global__ __launch_bounds__(256) void prop_select(
    const float* __restrict__ xprev,
    const int* __restrict__ ptr, const int* __restrict__ ccol,
    const float* __restrict__ cw, unsigned char* __restrict__ imp,
    const int* __restrict__ cap_arr, uint32_t k0, uint32_t k1,
    float* __restrict__ xnext) {
  #pragma clang fp contract(off)
  __shared__ int hist_s[4][256];
  int wv = threadIdx.x >> 6;
  int lane = threadIdx.x & 63;
  int r = blockIdx.x * 4 + wv;
  if (r >= N_NODES) return;
  int beg = ptr[r], end = ptr[r + 1];
  int* h = hist_s[wv];

  // ---- gather-accumulate xp for this row (f32, exact ascending edge order,
  //      2-edge software pipeline: 4 loads in flight, acc chain order kept) ----
  float4 acc0 = make_float4(0.f, 0.f, 0.f, 0.f);
  float4 acc1 = make_float4(0.f, 0.f, 0.f, 0.f);
  for (int base = beg; base < end; base += 64) {
    int n = min(64, end - base);
    int c = 0; float wt = 0.f;
    if (lane < n) { c = ccol[base + lane]; wt = cw[base + lane]; }
    int i = 0;
    for (; i + 1 < n; i += 2) {
      int ci0 = __shfl(c, i, 64);
      int ci1 = __shfl(c, i + 1, 64);
      float wi0 = __shfl(wt, i, 64);
      float wi1 = __shfl(wt, i + 1, 64);
      const float4* xr0 = (const float4*)(xprev + (size_t)ci0 * N_GENES);
      const float4* xr1 = (const float4*)(xprev + (size_t)ci1 * N_GENES);
      float4 a0 = xr0[lane], b0 = xr0[64 + lane];
      float4 a1 = xr1[lane], b1 = xr1[64 + lane];
      acc0.x = acc0.x + wi0 * a0.x;  acc0.y = acc0.y + wi0 * a0.y;
      acc0.z = acc0.z + wi0 * a0.z;  acc0.w = acc0.w + wi0 * a0.w;
      acc1.x = acc1.x + wi0 * b0.x;  acc1.y = acc1.y + wi0 * b0.y;
      acc1.z = acc1.z + wi0 * b0.z;  acc1.w = acc1.w + wi0 * b0.w;
      acc0.x = acc0.x + wi1 * a1.x;  acc0.y = acc0.y + wi1 * a1.y;
      acc0.z = acc0.z + wi1 * a1.z;  acc0.w = acc0.w + wi1 * a1.w;
      acc1.x = acc1.x + wi1 * b1.x;  acc1.y = acc1.y + wi1 * b1.y;
      acc1.z = acc1.z + wi1 * b1.z;  acc1.w = acc1.w + wi1 * b1.w;
    }
    if (i < n) {
      int ci = __shfl(c, i, 64);
      float wi = __shfl(wt, i, 64);
      const float4* xr = (const float4*)(xprev + (size_t)ci * N_GENES);
      float4 a = xr[lane], b = xr[64 + lane];
      acc0.x = acc0.x + wi * a.x;  acc0.y = acc0.y + wi * a.y;
      acc0.z = acc0.z + wi * a.z;  acc0.w = acc0.w + wi * a.w;
      acc1.x = acc1.x + wi * b.x;  acc1.y = acc1.y + wi * b.y;
      acc1.z = acc1.z + wi * b.z;  acc1.w = acc1.w + wi * b.w;
    }
  }

  // ---- merge using xprev row r + imp bits (existing entries win) ----
  size_t rowoff = (size_t)r * N_GENES;
  unsigned char ibyte = imp[(size_t)r * 64 + lane];
  const float4* p4 = (const float4*)(xprev + rowoff);
  float4 pa = p4[lane], pb = p4[64 + lane];
  float pv[8] = {pa.x, pa.y, pa.z, pa.w, pb.x, pb.y, pb.z, pb.w};
  float av[8] = {acc0.x, acc0.y, acc0.z, acc0.w, acc1.x, acc1.y, acc1.z, acc1.w};
  float val[8];
  bool ex[8];
  #pragma unroll
  for (int j = 0; j < 8; ++j) {
    ex[j] = (pv[j] != 0.f) && !((ibyte >> j) & 1);   // == (orig[j] != 0)
    val[j] = ex[j] ? pv[j] : av[j];
  }

  // ---- valid mask & count ----
  bool valid[8];
  int cnt_local = 0;
  #pragma unroll
  for (int j = 0; j < 8; ++j) {
    bool im = ((ibyte >> j) & 1) || ((val[j] != 0.f) && !ex[j]);
    valid[j] = im;
    cnt_local += im ? 1 : 0;
  }
  int nimp = cnt_local;
  #pragma unroll
  for (int off = 32; off > 0; off >>= 1) nimp += __shfl_xor(nimp, off, 64);
  int cap = cap_arr[r];

  bool keep_all = (nimp <= cap);
  bool keep_none = (!keep_all) && (cap <= 0);
  uint32_t key[8];
  uint32_t T = 0;
  bool use_T = false;

  if (!keep_all && !keep_none) {   // wave-uniform branch
    // keys (partitionable PRNG; (score23, gene) lexicographic, distinct)
    #pragma unroll
    for (int j = 0; j < 8; ++j) {
      int g = (j < 4) ? (4 * lane + j) : (256 + 4 * lane + (j - 4));
      uint32_t b = jax_bits_part32(k0, k1, (uint32_t)rowoff + (uint32_t)g);
      key[j] = ((b >> 9) << 9) | (uint32_t)g;
    }
    // histogram on top-8 bits (wave-private LDS, transposed layout)
    h[lane] = 0; h[lane + 64] = 0; h[lane + 128] = 0; h[lane + 192] = 0;
    #pragma unroll
    for (int j = 0; j < 8; ++j)
      if (valid[j]) atomicAdd(&h[tr(key[j] >> 24)], 1);
    __threadfence_block();
    // lane owns buckets 4*lane .. 4*lane+3 (conflict-free reads via tr)
    int c0 = h[lane], c1 = h[64 + lane], c2 = h[128 + lane], c3 = h[192 + lane];
    int lsum = c0 + c1 + c2 + c3;
    int incl = lsum;
    #pragma unroll
    for (int off = 1; off < 64; off <<= 1) {
      int v = __shfl_up(incl, off, 64);
      if (lane >= off) incl += v;
    }
    int excl = incl - lsum;   // count of valid keys in buckets < 4*lane
    // locate bucket containing the cap-th smallest (1 <= cap < nimp here)
    int foundB = -1, foundRem = 0, cum = excl;
    if (cap > cum && cap <= cum + c0) { foundB = 4 * lane;     foundRem = cap - cum; } cum += c0;
    if (foundB < 0 && cap > cum && cap <= cum + c1) { foundB = 4 * lane + 1; foundRem = cap - cum; } cum += c1;
    if (foundB < 0 && cap > cum && cap <= cum + c2) { foundB = 4 * lane + 2; foundRem = cap - cum; } cum += c2;
    if (foundB < 0 && cap > cum && cap <= cum + c3) { foundB = 4 * lane + 3; foundRem = cap - cum; }
    unsigned long long mb = __ballot(foundB >= 0);
    int src = __ffsll(mb) - 1;
    int B   = __shfl(foundB, src, 64);
    int rem = __shfl(foundRem, src, 64);
    // candidates in bucket B; extract min `rem` times (keys distinct)
    unsigned cm = 0;
    #pragma unroll
    for (int j = 0; j < 8; ++j)
      if (valid[j] && (int)(key[j] >> 24) == B) cm |= (1u << j);
    for (;;) {
      uint32_t m = 0xFFFFFFFFu;
      #pragma unroll
      for (int j = 0; j < 8; ++j)
        if (cm & (1u << j)) m = min(m, key[j]);
      #pragma unroll
      for (int off = 32; off > 0; off >>= 1)
        m = min(m, (uint32_t)__shfl_xor((int)m, off, 64));
      if (rem == 1) { T = m; break; }
      #pragma unroll
      for (int j = 0; j < 8; ++j)
        if ((cm & (1u << j)) && key[j] == m) cm &= ~(1u << j);
      rem--;
    }
    use_T = true;
  }

  // ---- apply & write ----
  float rv[8]; unsigned char ob8 = 0;
  #pragma unroll
  for (int j = 0; j < 8; ++j) {
    bool keep = valid[j] && (keep_all || (use_T && key[j] <= T));
    ob8 |= (unsigned char)(keep ? (1u << j) : 0u);
    rv[j] = (valid[j] && !keep) ? 0.f : val[j];
  }
  float4* x4 = (float4*)(xnext + rowoff);
  x4[lane]      = make_float4(rv[0], rv[1], rv[2], rv[3]);
  x4[64 + lane] = make_float4(rv[4], rv[5], rv[6], rv[7]);
  imp[(size_t)r * 64 + lane] = ob8;
}

// diagnostic: only fires if workspace is smaller than we need
__global__ void ws_probe(float* out, unsigned long long ws_bytes, unsigned long long needed) {
  if (ws_bytes < needed) out[0] = (float)ws_bytes;
}

extern "C" void kernel_launch(void* const* d_in, const int* in_sizes, int n_in,
                              void* d_out, int out_size, void* d_ws, size_t ws_size,
                              hipStream_t stream) {
  const float* x_in = (const float*)d_in[0];
  const float* ew   = (const float*)d_in[1];
  const int*   ei   = (const int*)d_in[2];
  const int*   cap  = (const int*)d_in[3];
  const int* rows = ei;
  const int* cols = ei + N_EDGES;
  float* out = (float*)d_out;

  char* ws = (char*)d_ws;
  float* x_ws = (float*)ws;                 ws += X_WS_BYTES;
  unsigned char* imp = (unsigned char*)ws;  ws += IMP_BYTES;
  int* cnt = (int*)ws;                      ws += CNT_BYTES;
  int* ptr = (int*)ws;                      ws += PTR_BYTES;
  int* ccol = (int*)ws;                     ws += CCOL_BYTES;
  float* cw = (float*)ws;                   ws += CW_BYTES;
  int* hist = (int*)d_ws;   // aliases x_ws: 50 MB, dead before x_ws first written

  hipMemsetAsync(hist, 0, (size_t)C_CHUNKS * N_NODES * sizeof(int), stream);
  hipMemsetAsync(imp, 0, IMP_BYTES, stream);

  chunk_hist<<<C_CHUNKS, 256, 0, stream>>>(rows, hist);
  row_scan<<<(N_NODES + 255) / 256, 256, 0, stream>>>(hist, cnt);
  scan_counts<<<1, 256, 0, stream>>>(cnt, ptr);
  scatter_par<<<C_CHUNKS, 64, 0, stream>>>(rows, cols, ew, ptr, hist, ccol, cw);

  // per-iteration keys: fold_in(key(42), it) = threefry2x32((0,42),(0,it))
  uint32_t key_it[N_ITERS][2];
  for (int it = 0; it < N_ITERS; ++it) {
    uint32_t o0, o1;
    threefry2x32(0u, 42u, 0u, (uint32_t)it, o0, o1);
    key_it[it][0] = o0; key_it[it][1] = o1;
  }

  const float* xp = x_in;
  float* buf[2] = {out, x_ws};  // it0->out, it1->ws, it2->out, it3->ws, it4->out
  for (int it = 0; it < N_ITERS; ++it) {
    float* xn = buf[it & 1];
    prop_select<<<N_NODES / 4, 256, 0, stream>>>(xp, ptr, ccol, cw, imp, cap,
                                                 key_it[it][0], key_it[it][1], xn);
    xp = xn;
  }

  ws_probe<<<1, 1, 0, stream>>>(out, (unsigned long long)ws_size,
                                (unsigned long long)WS_NEEDED);
}

// Round 9
// 1714.899 us; speedup vs baseline: 1.0013x; 1.0013x over previous
//
#include <hip/hip_runtime.h>
#include <stdint.h>

#define N_NODES   50000
#define N_GENES   512
#define N_EDGES   800000
#define N_ITERS   5
#define TOTAL_ELEMS 25600000u

#define C_CHUNKS  250
#define CHUNK_E   3200          // 250 * 3200 = 800000; 3200/64 = 50 subchunks exactly

// ws layout sizes (bytes)
#define X_WS_BYTES   102400000ull
#define IMP_BYTES    3200000ull            // 64 B per row: byte per lane, 8 gene-flags/bit
#define CNT_BYTES    200000ull
#define PTR_BYTES    200004ull
#define CCOL_BYTES   3200000ull
#define CW_BYTES     3200000ull
#define WS_NEEDED (X_WS_BYTES + IMP_BYTES + CNT_BYTES + PTR_BYTES + CCOL_BYTES + CW_BYTES)
// hist (250*50000*4 = 50 MB) aliases the x_ws region: dead before x_ws first written.

// ---------- JAX threefry2x32 (20 rounds), exact replica ----------
__host__ __device__ __forceinline__ uint32_t rotl32(uint32_t x, int r) {
  return (x << r) | (x >> (32 - r));
}

__host__ __device__ __forceinline__ void threefry2x32(uint32_t k0, uint32_t k1,
                                                      uint32_t x0, uint32_t x1,
                                                      uint32_t& o0, uint32_t& o1) {
  uint32_t k2 = k0 ^ k1 ^ 0x1BD11BDAu;
  x0 += k0; x1 += k1;
  x0 += x1; x1 = rotl32(x1, 13) ^ x0;
  x0 += x1; x1 = rotl32(x1, 15) ^ x0;
  x0 += x1; x1 = rotl32(x1, 26) ^ x0;
  x0 += x1; x1 = rotl32(x1, 6)  ^ x0;
  x0 += k1; x1 += k2 + 1u;
  x0 += x1; x1 = rotl32(x1, 17) ^ x0;
  x0 += x1; x1 = rotl32(x1, 29) ^ x0;
  x0 += x1; x1 = rotl32(x1, 16) ^ x0;
  x0 += x1; x1 = rotl32(x1, 24) ^ x0;
  x0 += k2; x1 += k0 + 2u;
  x0 += x1; x1 = rotl32(x1, 13) ^ x0;
  x0 += x1; x1 = rotl32(x1, 15) ^ x0;
  x0 += x1; x1 = rotl32(x1, 26) ^ x0;
  x0 += x1; x1 = rotl32(x1, 6)  ^ x0;
  x0 += k0; x1 += k1 + 3u;
  x0 += x1; x1 = rotl32(x1, 17) ^ x0;
  x0 += x1; x1 = rotl32(x1, 29) ^ x0;
  x0 += x1; x1 = rotl32(x1, 16) ^ x0;
  x0 += x1; x1 = rotl32(x1, 24) ^ x0;
  x0 += k1; x1 += k2 + 4u;
  x0 += x1; x1 = rotl32(x1, 13) ^ x0;
  x0 += x1; x1 = rotl32(x1, 15) ^ x0;
  x0 += x1; x1 = rotl32(x1, 26) ^ x0;
  x0 += x1; x1 = rotl32(x1, 6)  ^ x0;
  x0 += k2; x1 += k0 + 5u;
  o0 = x0; o1 = x1;
}

// threefry_partitionable=True (modern JAX default) 32-bit random bits:
// counter-mode over the 64-bit flat index j -> (0, j); xor-fold: o0 ^ o1.
__device__ __forceinline__ uint32_t jax_bits_part32(uint32_t k0, uint32_t k1, uint32_t j) {
  uint32_t o0, o1;
  threefry2x32(k0, k1, 0u, j, o0, o1);
  return o0 ^ o1;
}

// ---------- order-preserving CSR build ----------
__global__ void chunk_hist(const int* __restrict__ rows, int* __restrict__ hist) {
  int c = blockIdx.x;
  int base = c * CHUNK_E;
  int* h = hist + (size_t)c * N_NODES;
  for (int i = threadIdx.x; i < CHUNK_E; i += blockDim.x)
    atomicAdd(&h[rows[base + i]], 1);
}

// per-row exclusive scan across chunks; emits per-row totals
__global__ void row_scan(int* __restrict__ hist, int* __restrict__ cnt) {
  int r = blockIdx.x * blockDim.x + threadIdx.x;
  if (r >= N_NODES) return;
  int run = 0;
  for (int c = 0; c < C_CHUNKS; ++c) {
    size_t idx = (size_t)c * N_NODES + r;
    int t = hist[idx];
    hist[idx] = run;
    run += t;
  }
  cnt[r] = run;
}

__global__ void scan_counts(int* __restrict__ cnt, int* __restrict__ ptr) {
  const int T = 256;
  const int CH = (N_NODES + T - 1) / T;  // 196
  __shared__ int sums[T];
  int t = threadIdx.x;
  int lo = t * CH;
  int hi = min(lo + CH, N_NODES);
  int s = 0;
  for (int i = lo; i < hi; ++i) s += cnt[i];
  sums[t] = s;
  __syncthreads();
  for (int off = 1; off < T; off <<= 1) {
    int u = (t >= off) ? sums[t - off] : 0;
    __syncthreads();
    sums[t] += u;
    __syncthreads();
  }
  int run = sums[t] - s;
  for (int i = lo; i < hi; ++i) { int c = cnt[i]; ptr[i] = run; run += c; }
  if (t == T - 1) ptr[N_NODES] = run;
}

// parallel order-preserving scatter: one wave per chunk (see R6 notes).
__global__ __launch_bounds__(64) void scatter_par(
    const int* __restrict__ rows, const int* __restrict__ cols,
    const float* __restrict__ w, const int* __restrict__ ptr,
    int* __restrict__ hist, int* __restrict__ ccol, float* __restrict__ cw) {
  int c = blockIdx.x;
  int lane = threadIdx.x;
  int* h = hist + (size_t)c * N_NODES;
  int base = c * CHUNK_E;
  for (int sub = 0; sub < CHUNK_E / 64; ++sub) {
    int e = base + sub * 64 + lane;
    int r = rows[e];
    int rank = 0, count = 0, lastlane = 0;
    #pragma unroll 8
    for (int i = 0; i < 64; ++i) {
      int ri = __shfl(r, i, 64);
      if (ri == r) {
        count++;
        if (i < lane) rank++;
        lastlane = i;          // i ascending -> ends at max matching lane
      }
    }
    int old = 0;
    if (lane == lastlane) old = atomicAdd(&h[r], count);
    old = __shfl(old, lastlane, 64);   // data dep -> vmcnt drain before next sub
    int pos = ptr[r] + old + rank;
    ccol[pos] = cols[e];
    cw[pos]   = w[e];
  }
}

// transposed LDS index for bucket b: stride-64 across a lane's 4 buckets
__device__ __forceinline__ int tr(uint32_t b) {
  return (int)(((b & 3u) << 6) | (b >> 2));
}

#define EDGE_FMA(W, A, B)                                                 \
  acc0.x = acc0.x + (W) * (A).x;  acc0.y = acc0.y + (W) * (A).y;          \
  acc0.z = acc0.z + (W) * (A).z;  acc0.w = acc0.w + (W) * (A).w;          \
  acc1.x = acc1.x + (W) * (B).x;  acc1.y = acc1.y + (W) * (B).y;          \
  acc1.z = acc1.z + (W) * (B).z;  acc1.w = acc1.w + (W) * (B).w;

// ---------- fused propagate + select: one wave per row ----------
// orig-free merge: existing <=> xprev[j]!=0 && !impbit[j].
// XLA-CPU scatter semantics: ascending edge order, mul/add rounded separately;
// unroll-4 gather = 8 float4 loads in flight, per-gene add chain order kept.
__global__ __launch_bounds__(256) void prop_select(
    const float* __restrict__ xprev,
    const int* __restrict__ ptr, const int* __restrict__ ccol,
    const float* __restrict__ cw, unsigned char* __restrict__ imp,
    const int* __restrict__ cap_arr, uint32_t k0, uint32_t k1,
    float* __restrict__ xnext) {
  #pragma clang fp contract(off)
  __shared__ int hist_s[4][256];
  int wv = threadIdx.x >> 6;
  int lane = threadIdx.x & 63;
  int r = blockIdx.x * 4 + wv;
  if (r >= N_NODES) return;
  int beg = ptr[r], end = ptr[r + 1];
  int* h = hist_s[wv];

  // hoist row-r merge inputs: overlap their latency with the gather
  size_t rowoff = (size_t)r * N_GENES;
  unsigned char ibyte = imp[(size_t)r * 64 + lane];
  const float4* p4 = (const float4*)(xprev + rowoff);
  float4 pa = p4[lane], pb = p4[64 + lane];
  int cap = cap_arr[r];

  // ---- gather-accumulate xp for this row (f32, exact ascending edge order) ----
  float4 acc0 = make_float4(0.f, 0.f, 0.f, 0.f);
  float4 acc1 = make_float4(0.f, 0.f, 0.f, 0.f);
  for (int base = beg; base < end; base += 64) {
    int n = min(64, end - base);
    int c = 0; float wt = 0.f;
    if (lane < n) { c = ccol[base + lane]; wt = cw[base + lane]; }
    int i = 0;
    for (; i + 3 < n; i += 4) {
      int ci0 = __shfl(c, i, 64);
      int ci1 = __shfl(c, i + 1, 64);
      int ci2 = __shfl(c, i + 2, 64);
      int ci3 = __shfl(c, i + 3, 64);
      float wi0 = __shfl(wt, i, 64);
      float wi1 = __shfl(wt, i + 1, 64);
      float wi2 = __shfl(wt, i + 2, 64);
      float wi3 = __shfl(wt, i + 3, 64);
      const float4* xr0 = (const float4*)(xprev + (size_t)ci0 * N_GENES);
      const float4* xr1 = (const float4*)(xprev + (size_t)ci1 * N_GENES);
      const float4* xr2 = (const float4*)(xprev + (size_t)ci2 * N_GENES);
      const float4* xr3 = (const float4*)(xprev + (size_t)ci3 * N_GENES);
      float4 a0 = xr0[lane], b0 = xr0[64 + lane];
      float4 a1 = xr1[lane], b1 = xr1[64 + lane];
      float4 a2 = xr2[lane], b2 = xr2[64 + lane];
      float4 a3 = xr3[lane], b3 = xr3[64 + lane];
      EDGE_FMA(wi0, a0, b0)
      EDGE_FMA(wi1, a1, b1)
      EDGE_FMA(wi2, a2, b2)
      EDGE_FMA(wi3, a3, b3)
    }
    for (; i < n; ++i) {
      int ci = __shfl(c, i, 64);
      float wi = __shfl(wt, i, 64);
      const float4* xr = (const float4*)(xprev + (size_t)ci * N_GENES);
      float4 a = xr[lane], b = xr[64 + lane];
      EDGE_FMA(wi, a, b)
    }
  }

  // ---- merge using xprev row r + imp bits (existing entries win) ----
  float pv[8] = {pa.x, pa.y, pa.z, pa.w, pb.x, pb.y, pb.z, pb.w};
  float av[8] = {acc0.x, acc0.y, acc0.z, acc0.w, acc1.x, acc1.y, acc1.z, acc1.w};
  float val[8];
  bool ex[8];
  #pragma unroll
  for (int j = 0; j < 8; ++j) {
    ex[j] = (pv[j] != 0.f) && !((ibyte >> j) & 1);   // == (orig[j] != 0)
    val[j] = ex[j] ? pv[j] : av[j];
  }

  // ---- valid mask & count ----
  bool valid[8];
  int cnt_local = 0;
  #pragma unroll
  for (int j = 0; j < 8; ++j) {
    bool im = ((ibyte >> j) & 1) || ((val[j] != 0.f) && !ex[j]);
    valid[j] = im;
    cnt_local += im ? 1 : 0;
  }
  int nimp = cnt_local;
  #pragma unroll
  for (int off = 32; off > 0; off >>= 1) nimp += __shfl_xor(nimp, off, 64);

  bool keep_all = (nimp <= cap);
  bool keep_none = (!keep_all) && (cap <= 0);
  uint32_t key[8];
  uint32_t T = 0;
  bool use_T = false;

  if (!keep_all && !keep_none) {   // wave-uniform branch
    // keys (partitionable PRNG; (score23, gene) lexicographic, distinct)
    #pragma unroll
    for (int j = 0; j < 8; ++j) {
      int g = (j < 4) ? (4 * lane + j) : (256 + 4 * lane + (j - 4));
      uint32_t b = jax_bits_part32(k0, k1, (uint32_t)rowoff + (uint32_t)g);
      key[j] = ((b >> 9) << 9) | (uint32_t)g;
    }
    // histogram on top-8 bits (wave-private LDS, transposed layout)
    h[lane] = 0; h[lane + 64] = 0; h[lane + 128] = 0; h[lane + 192] = 0;
    #pragma unroll
    for (int j = 0; j < 8; ++j)
      if (valid[j]) atomicAdd(&h[tr(key[j] >> 24)], 1);
    __threadfence_block();
    // lane owns buckets 4*lane .. 4*lane+3 (conflict-free reads via tr)
    int c0 = h[lane], c1 = h[64 + lane], c2 = h[128 + lane], c3 = h[192 + lane];
    int lsum = c0 + c1 + c2 + c3;
    int incl = lsum;
    #pragma unroll
    for (int off = 1; off < 64; off <<= 1) {
      int v = __shfl_up(incl, off, 64);
      if (lane >= off) incl += v;
    }
    int excl = incl - lsum;   // count of valid keys in buckets < 4*lane
    // locate bucket containing the cap-th smallest (1 <= cap < nimp here)
    int foundB = -1, foundRem = 0, cum = excl;
    if (cap > cum && cap <= cum + c0) { foundB = 4 * lane;     foundRem = cap - cum; } cum += c0;
    if (foundB < 0 && cap > cum && cap <= cum + c1) { foundB = 4 * lane + 1; foundRem = cap - cum; } cum += c1;
    if (foundB < 0 && cap > cum && cap <= cum + c2) { foundB = 4 * lane + 2; foundRem = cap - cum; } cum += c2;
    if (foundB < 0 && cap > cum && cap <= cum + c3) { foundB = 4 * lane + 3; foundRem = cap - cum; }
    unsigned long long mb = __ballot(foundB >= 0);
    int src = __ffsll(mb) - 1;
    int B   = __shfl(foundB, src, 64);
    int rem = __shfl(foundRem, src, 64);
    // candidates in bucket B; extract min `rem` times (keys distinct)
    unsigned cm = 0;
    #pragma unroll
    for (int j = 0; j < 8; ++j)
      if (valid[j] && (int)(key[j] >> 24) == B) cm |= (1u << j);
    for (;;) {
      uint32_t m = 0xFFFFFFFFu;
      #pragma unroll
      for (int j = 0; j < 8; ++j)
        if (cm & (1u << j)) m = min(m, key[j]);
      #pragma unroll
      for (int off = 32; off > 0; off >>= 1)
        m = min(m, (uint32_t)__shfl_xor((int)m, off, 64));
      if (rem == 1) { T = m; break; }
      #pragma unroll
      for (int j = 0; j < 8; ++j)
        if ((cm & (1u << j)) && key[j] == m) cm &= ~(1u << j);
      rem--;
    }
    use_T = true;
  }

  // ---- apply & write ----
  float rv[8]; unsigned char ob8 = 0;
  #pragma unroll
  for (int j = 0; j < 8; ++j) {
    bool keep = valid[j] && (keep_all || (use_T && key[j] <= T));
    ob8 |= (unsigned char)(keep ? (1u << j) : 0u);
    rv[j] = (valid[j] && !keep) ? 0.f : val[j];
  }
  float4* x4 = (float4*)(xnext + rowoff);
  x4[lane]      = make_float4(rv[0], rv[1], rv[2], rv[3]);
  x4[64 + lane] = make_float4(rv[4], rv[5], rv[6], rv[7]);
  imp[(size_t)r * 64 + lane] = ob8;
}

// diagnostic: only fires if workspace is smaller than we need
__global__ void ws_probe(float* out, unsigned long long ws_bytes, unsigned long long needed) {
  if (ws_bytes < needed) out[0] = (float)ws_bytes;
}

extern "C" void kernel_launch(void* const* d_in, const int* in_sizes, int n_in,
                              void* d_out, int out_size, void* d_ws, size_t ws_size,
                              hipStream_t stream) {
  const float* x_in = (const float*)d_in[0];
  const float* ew   = (const float*)d_in[1];
  const int*   ei   = (const int*)d_in[2];
  const int*   cap  = (const int*)d_in[3];
  const int* rows = ei;
  const int* cols = ei + N_EDGES;
  float* out = (float*)d_out;

  char* ws = (char*)d_ws;
  float* x_ws = (float*)ws;                 ws += X_WS_BYTES;
  unsigned char* imp = (unsigned char*)ws;  ws += IMP_BYTES;
  int* cnt = (int*)ws;                      ws += CNT_BYTES;
  int* ptr = (int*)ws;                      ws += PTR_BYTES;
  int* ccol = (int*)ws;                     ws += CCOL_BYTES;
  float* cw = (float*)ws;                   ws += CW_BYTES;
  int* hist = (int*)d_ws;   // aliases x_ws: 50 MB, dead before x_ws first written

  hipMemsetAsync(hist, 0, (size_t)C_CHUNKS * N_NODES * sizeof(int), stream);
  hipMemsetAsync(imp, 0, IMP_BYTES, stream);

  chunk_hist<<<C_CHUNKS, 256, 0, stream>>>(rows, hist);
  row_scan<<<(N_NODES + 255) / 256, 256, 0, stream>>>(hist, cnt);
  scan_counts<<<1, 256, 0, stream>>>(cnt, ptr);
  scatter_par<<<C_CHUNKS, 64, 0, stream>>>(rows, cols, ew, ptr, hist, ccol, cw);

  // per-iteration keys: fold_in(key(42), it) = threefry2x32((0,42),(0,it))
  uint32_t key_it[N_ITERS][2];
  for (int it = 0; it < N_ITERS; ++it) {
    uint32_t o0, o1;
    threefry2x32(0u, 42u, 0u, (uint32_t)it, o0, o1);
    key_it[it][0] = o0; key_it[it][1] = o1;
  }

  const float* xp = x_in;
  float* buf[2] = {out, x_ws};  // it0->out, it1->ws, it2->out, it3->ws, it4->out
  for (int it = 0; it < N_ITERS; ++it) {
    float* xn = buf[it & 1];
    prop_select<<<N_NODES / 4, 256, 0, stream>>>(xp, ptr, ccol, cw, imp, cap,
                                                 key_it[it][0], key_it[it][1], xn);
    xp = xn;
  }

  ws_probe<<<1, 1, 0, stream>>>(out, (unsigned long long)ws_size,
                                (unsigned long long)WS_NEEDED);
}